// Round 8
// baseline (305.296 us; speedup 1.0000x reference)
//
#include <hip/hip_runtime.h>
#include <stdint.h>

#define DQ 128
#define CDIM 128
#define ROW_F 129              // places_db row stride in floats (128 + place_id)
#define N_DB 1000000
#define CHUNK 32               // db rows per chunk
#define NCHUNK (N_DB / CHUNK)  // 31250 exact
#define GRIDF 1024             // 4 blocks/CU
#define NTHRF 256              // 4 waves/block -> 16 waves/CU
#define CHUNK_FLOATS (CHUNK * ROW_F)  // 4128
#define WSPAN 1032             // floats per wave span = 8 rows exactly (8*129)
#define BF_STRIDE 136          // shorts per row (272 B): aligned + conflict-free b128
#define CAP 512
#define NTOP 10
#define MIN_SIM_F 0.8f

typedef __attribute__((ext_vector_type(8))) short bf16x8;
typedef __attribute__((ext_vector_type(4))) float f32x4;

// fp32 -> bf16 bits, round-to-nearest-even (A side only, once)
__device__ __forceinline__ short f2bf_rne(float x) {
  uint32_t u = __float_as_uint(x);
  u += 0x7FFFu + ((u >> 16) & 1u);
  return (short)(u >> 16);
}

// ---------------------------------------------------------------------------
// Register staging: wave w loads its span [1032w, 1032w+1032) of the chunk
// as 4x dwordx4/lane + 2-lane tail. Perfectly coalesced 16B loads; the
// compiler issues them early and waits (counted vmcnt) only at first use in
// pack_span one iteration later.
// ---------------------------------------------------------------------------
__device__ __forceinline__ void load_span(const float* __restrict__ src, int w,
                                          int lane, float4 m[4], float4* tail) {
  const float4* ps = (const float4*)(src + WSPAN * w);
#pragma unroll
  for (int k = 0; k < 4; ++k) m[k] = ps[64 * k + lane];
  if (lane < 2) *tail = ps[256 + lane];
}

// Pack one dwordx4 piece (4 floats at chunk-linear index F0) into the bf16
// tile: r = F/129, c = F%129; skip c==128 (place_id). Trunc-to-bf16.
// Addresses are loop-invariant per (w,lane,k); compiler CSEs the divmod.
__device__ __forceinline__ void pack_piece(short* bfb, int F0, float4 v) {
  int r = F0 / ROW_F;
  int c = F0 - r * ROW_F;
  const float vv[4] = {v.x, v.y, v.z, v.w};
#pragma unroll
  for (int j = 0; j < 4; ++j) {
    if (c == ROW_F) { r += 1; c = 0; }
    if (c < 128)
      bfb[r * BF_STRIDE + c] = (short)(__float_as_uint(vv[j]) >> 16);
    ++c;
  }
}

__device__ __forceinline__ void pack_span(short* bfb, int w, int lane,
                                          const float4 m[4], float4 tail) {
#pragma unroll
  for (int k = 0; k < 4; ++k)
    pack_piece(bfb, WSPAN * w + 256 * k + 4 * lane, m[k]);
  if (lane < 2) pack_piece(bfb, WSPAN * w + 1024 + 4 * lane, tail);
}

// Compute one chunk from the bf16 tile + threshold-append.
__device__ __forceinline__ void compute_chunk(
    const short* bfb, const bf16x8 afrag[2][4], const float tau_l[2][4],
    int chunk, int w, int r16, int kg, int* __restrict__ cnt,
    int* __restrict__ cand) {
  f32x4 acc[2][2];
  acc[0][0] = (f32x4){0.f, 0.f, 0.f, 0.f};
  acc[0][1] = (f32x4){0.f, 0.f, 0.f, 0.f};
  acc[1][0] = (f32x4){0.f, 0.f, 0.f, 0.f};
  acc[1][1] = (f32x4){0.f, 0.f, 0.f, 0.f};
#pragma unroll
  for (int ks = 0; ks < 4; ++ks) {
#pragma unroll
    for (int rt = 0; rt < 2; ++rt) {
      const bf16x8 b =
          *(const bf16x8*)(bfb + (rt * 16 + r16) * BF_STRIDE + ks * 32 + kg * 8);
      acc[0][rt] =
          __builtin_amdgcn_mfma_f32_16x16x32_bf16(afrag[0][ks], b, acc[0][rt], 0, 0, 0);
      acc[1][rt] =
          __builtin_amdgcn_mfma_f32_16x16x32_bf16(afrag[1][ks], b, acc[1][rt], 0, 0, 0);
    }
  }
#pragma unroll
  for (int qt = 0; qt < 2; ++qt)
#pragma unroll
    for (int rt = 0; rt < 2; ++rt)
#pragma unroll
      for (int reg = 0; reg < 4; ++reg) {
        const float sim = acc[qt][rt][reg];
        if (sim >= tau_l[qt][reg]) {
          const int q = (2 * w + qt) * 16 + kg * 4 + reg;
          const int row = chunk * CHUNK + rt * 16 + r16;
          const int pos = atomicAdd(&cnt[q], 1);
          if (pos < CAP) cand[q * CAP + pos] = row;
        }
      }
}

#define PUBLISH()                                          \
  do {                                                     \
    asm volatile("s_waitcnt lgkmcnt(0)" ::: "memory");     \
    __builtin_amdgcn_s_barrier();                          \
    asm volatile("" ::: "memory");                         \
  } while (0)

// ---------------------------------------------------------------------------
// Filter: register-staged, LDS-scratch-free pipeline. Per iter (unroll 2):
//   load(i+2) -> regs (coalesced dwordx4, compiler-managed vmcnt)
//   compute(i) from bfb[cur]
//   pack(i+1): regs -> bfb[nxt]   (b16 scatter, once per chunk)
//   lgkmcnt(0); raw s_barrier     (no vmcnt drain: loads stay in flight)
// LDS = 18 KB -> 4 blocks/CU; no stage/pack LDS round-trip.
// ---------------------------------------------------------------------------
__global__ __launch_bounds__(NTHRF, 4) void filter_kernel(
    const float* __restrict__ desc, const float* __restrict__ pdb,
    int* __restrict__ cnt, int* __restrict__ cand) {
  __shared__ float tau_s[DQ];
  __shared__ __align__(16) short bfb0[CHUNK * BF_STRIDE];
  __shared__ __align__(16) short bfb1[CHUNK * BF_STRIDE];

  const int t = threadIdx.x;
  const int w = t >> 6;       // wave 0..3
  const int lane = t & 63;
  const int r16 = lane & 15;  // db-row within 16-tile (C col)
  const int kg = lane >> 4;   // k-group / C row-group

  const int bid = blockIdx.x;
  const int C = (NCHUNK - bid + GRIDF - 1) / GRIDF;

  float4 mA[4], tA{}, mB[4], tB{};

  // Chunk 0 loads in flight immediately.
  load_span(pdb + (size_t)bid * CHUNK_FLOATS, w, lane, mA, &tA);

  // Fused prep: tau[q] = 3.8*||desc_q|| - 2.0 (cut ~3.62 sigma; true top-10
  // ~4.26 sigma; margin covers bf16 A(RNE)+B(trunc) dot error).
  if (t < DQ) {
    const float4* dp = (const float4*)(desc + t * CDIM);
    float ssq = 0.f;
#pragma unroll
    for (int c = 0; c < 32; ++c) {
      const float4 v = dp[c];
      ssq = fmaf(v.x, v.x, ssq);
      ssq = fmaf(v.y, v.y, ssq);
      ssq = fmaf(v.z, v.z, ssq);
      ssq = fmaf(v.w, v.w, ssq);
    }
    tau_s[t] = 3.8f * sqrtf(ssq) - 2.0f;
  }

  // A fragments: wave w owns qtiles {2w, 2w+1} (queries 32w..32w+31).
  bf16x8 afrag[2][4];
#pragma unroll
  for (int qt = 0; qt < 2; ++qt) {
    const int q = (2 * w + qt) * 16 + r16;
#pragma unroll
    for (int ks = 0; ks < 4; ++ks) {
      const float* ap = desc + q * CDIM + ks * 32 + kg * 8;
      bf16x8 a;
#pragma unroll
      for (int j = 0; j < 8; ++j) a[j] = f2bf_rne(ap[j]);
      afrag[qt][ks] = a;
    }
  }

  // pack(0) (auto-waits chunk-0 regs), publish bfb0 + tau.
  pack_span(bfb0, w, lane, mA, tA);
  PUBLISH();
  if (C > 1) load_span(pdb + (size_t)(bid + GRIDF) * CHUNK_FLOATS, w, lane, mB, &tB);

  float tau_l[2][4];
#pragma unroll
  for (int qt = 0; qt < 2; ++qt)
#pragma unroll
    for (int r = 0; r < 4; ++r)
      tau_l[qt][r] = tau_s[(2 * w + qt) * 16 + kg * 4 + r];

  for (int i = 0; i < C; i += 2) {
    // even sub-iter: compute bfb0; load(i+2)->mA; pack mB->bfb1
    if (i + 2 < C)
      load_span(pdb + (size_t)(bid + (i + 2) * GRIDF) * CHUNK_FLOATS, w, lane, mA, &tA);
    compute_chunk(bfb0, afrag, tau_l, bid + i * GRIDF, w, r16, kg, cnt, cand);
    if (i + 1 < C) pack_span(bfb1, w, lane, mB, tB);
    PUBLISH();

    if (i + 1 >= C) break;

    // odd sub-iter: compute bfb1; load(i+3)->mB; pack mA->bfb0
    if (i + 3 < C)
      load_span(pdb + (size_t)(bid + (i + 3) * GRIDF) * CHUNK_FLOATS, w, lane, mB, &tB);
    compute_chunk(bfb1, afrag, tau_l, bid + (i + 1) * GRIDF, w, r16, kg, cnt, cand);
    if (i + 2 < C) pack_span(bfb0, w, lane, mA, tA);
    PUBLISH();
  }
}

// ---------------------------------------------------------------------------
// Finalize: one wave per query. Exact fp32 rescore, wave-parallel top-10,
// exact reference voting on lane 0.
// ---------------------------------------------------------------------------
__global__ void finalize_kernel(const float* __restrict__ boxes,
                                const float* __restrict__ desc,
                                const float* __restrict__ pdb,
                                const int* __restrict__ cnt,
                                const int* __restrict__ cand,
                                float* __restrict__ out) {
  const int q = blockIdx.x;
  const int lane = threadIdx.x;
  __shared__ float dq[CDIM];
  __shared__ float simsL[CAP];
  __shared__ int idxL[CAP];

  dq[lane] = desc[q * CDIM + lane];
  dq[lane + 64] = desc[q * CDIM + 64 + lane];
  __syncthreads();

  int n = cnt[q];
  if (n > CAP) n = CAP;
  for (int ci = lane; ci < n; ci += 64) {
    const int row = cand[q * CAP + ci];
    const float* xp = pdb + (long long)row * ROW_F;
    float s = 0.f;
#pragma unroll 16
    for (int c = 0; c < CDIM; ++c) s = fmaf(dq[c], xp[c], s);
    simsL[ci] = s;
    idxL[ci] = row;
  }
  __syncthreads();

  if (lane < 4) out[q * 4 + lane] = boxes[q * 4 + lane];

  float ts[NTOP];
  int ti[NTOP];
  for (int k = 0; k < NTOP; ++k) {
    float bv = -3e38f;
    int ba = -1;
    for (int ci = lane; ci < n; ci += 64)
      if (simsL[ci] > bv) { bv = simsL[ci]; ba = ci; }
#pragma unroll
    for (int off = 32; off; off >>= 1) {
      const float ov = __shfl_xor(bv, off);
      const int oa = __shfl_xor(ba, off);
      if (ov > bv) { bv = ov; ba = oa; }
    }
    ts[k] = bv;
    ti[k] = (ba >= 0) ? idxL[ba] : -1;
    if (lane == 0 && ba >= 0) simsL[ba] = -3e38f;
    __syncthreads();
  }

  if (lane == 0) {
    int pl[NTOP]; bool mk[NTOP];
    int n_kept = 0;
    for (int k = 0; k < NTOP; ++k) {
      pl[k] = (ti[k] >= 0) ? (int)pdb[(long long)ti[k] * ROW_F + CDIM] : -2;
      mk[k] = (ti[k] >= 0) && (ts[k] >= MIN_SIM_F);
      n_kept += mk[k] ? 1 : 0;
    }
    int maxc = 0;
    int counts[NTOP];
    for (int j = 0; j < NTOP; ++j) {
      int cj = 0;
      if (mk[j])
        for (int k = 0; k < NTOP; ++k)
          if (mk[k] && pl[k] == pl[j]) cj++;
      counts[j] = cj;
      if (cj > maxc) maxc = cj;
    }
    const int BIGC = 1 << 30;
    int majority = BIGC;
    for (int j = 0; j < NTOP; ++j)
      if (mk[j] && counts[j] == maxc && pl[j] < majority) majority = pl[j];
    const bool valid = (n_kept > 0);  // MIN_VOTES == 0
    const int cls = valid ? majority : -1;
    bool any = false;
    float best = -3e38f;
    for (int k = 0; k < NTOP; ++k)
      if (pl[k] == cls) {
        any = true;
        if (ts[k] > best) best = ts[k];
      }
    const float score = (valid && any) ? best : 0.f;
    out[512 + q] = score;
    out[640 + q] = (float)cls;
  }
}

extern "C" void kernel_launch(void* const* d_in, const int* in_sizes, int n_in,
                              void* d_out, int out_size, void* d_ws,
                              size_t ws_size, hipStream_t stream) {
  (void)in_sizes; (void)n_in; (void)out_size; (void)ws_size;
  const float* boxes = (const float*)d_in[0];
  const float* desc = (const float*)d_in[3];
  const float* pdb = (const float*)d_in[4];
  float* out = (float*)d_out;

  // ws layout: cnt[128] i32 @0 | cand[128*CAP] i32 @512
  int* cnt = (int*)d_ws;
  int* cand = (int*)((char*)d_ws + 512);

  hipMemsetAsync(cnt, 0, DQ * sizeof(int), stream);
  filter_kernel<<<GRIDF, NTHRF, 0, stream>>>(desc, pdb, cnt, cand);
  finalize_kernel<<<DQ, 64, 0, stream>>>(boxes, desc, pdb, cnt, cand, out);
}

// Round 9
// 140.973 us; speedup vs baseline: 2.1656x; 2.1656x over previous
//
#include <hip/hip_runtime.h>
#include <stdint.h>

#define DQ 128
#define CDIM 128
#define ROW_F 129              // places_db row stride in floats (128 + place_id)
#define N_DB 1000000
#define CHUNK 32               // db rows per chunk
#define NCHUNK (N_DB / CHUNK)  // 31250 exact
#define GRIDF 768              // 3 blocks/CU (LDS-capped)
#define NTHRF 256              // 4 waves/block -> 12 waves/CU
#define CHUNK_FLOATS (CHUNK * ROW_F)    // 4128 floats = 16512 B = 1032 slots
#define WAVE_SLOTS 258                  // 16B slots per wave = 8 rows exactly
#define BF_STRIDE 136                   // shorts per row (272 B) -> aligned + conflict-free b128
#define BFB_SHORTS (CHUNK * BF_STRIDE)  // 4352 shorts = 8704 B
#define CAP 512
#define NTOP 10
#define MIN_SIM_F 0.8f

typedef __attribute__((ext_vector_type(8))) short bf16x8;
typedef __attribute__((ext_vector_type(4))) float f32x4;
typedef __attribute__((ext_vector_type(4))) uint32_t u32x4;

#define AS1 __attribute__((address_space(1)))
#define AS3 __attribute__((address_space(3)))

// fp32 -> bf16 bits, round-to-nearest-even (A side only, once)
__device__ __forceinline__ short f2bf_rne(float x) {
  uint32_t u = __float_as_uint(x);
  u += 0x7FFFu + ((u >> 16) & 1u);
  return (short)(u >> 16);
}

// ---------------------------------------------------------------------------
// Wave-private stage: wave w DMAs slots [258w, 258w+258) of the linear chunk
// = floats [1032w, 1032w+1032) = rows 8w..8w+7 EXACTLY (1032 = 8*129).
// 5 global_load_lds per wave (4 full + 1 with lanes 0-1). Coalesced, aligned.
// ---------------------------------------------------------------------------
__device__ __forceinline__ void stage32(const float* __restrict__ src,
                                        float* scr, int w, int lane) {
  const int base = w * WAVE_SLOTS;
#pragma unroll
  for (int k = 0; k < 4; ++k) {
    const int s = base + 64 * k + lane;
    __builtin_amdgcn_global_load_lds((const AS1 void*)(src + 4 * s),
                                     (AS3 void*)(scr + 4 * (base + 64 * k)),
                                     16, 0, 0);
  }
  if (lane < 2) {
    const int s = base + 256 + lane;
    __builtin_amdgcn_global_load_lds((const AS1 void*)(src + 4 * s),
                                     (AS3 void*)(scr + 4 * (base + 256)),
                                     16, 0, 0);
  }
}

// ---------------------------------------------------------------------------
// Wave-private pack: wave w packs ITS OWN rows 8w..8w+7 (the ones it staged)
// from f32 scratch to the bf16 tile (trunc via v_perm). Lane l: row
// 8w+(l>>3), 16 cols at (l&7)*16. No cross-wave hazard -> no barrier needed
// between stage-land and pack; only the wave's own vmcnt.
// ---------------------------------------------------------------------------
__device__ __forceinline__ void pack32(const float* scr, short* bfb, int w,
                                       int lane) {
  const int r = 8 * w + (lane >> 3);
  const int cb = lane & 7;
  const float* rp = scr + r * ROW_F + cb * 16;
  uint32_t d[8];
#pragma unroll
  for (int i = 0; i < 8; ++i) {
    const uint32_t ue = __float_as_uint(rp[2 * i]);
    const uint32_t uo = __float_as_uint(rp[2 * i + 1]);
    d[i] = __builtin_amdgcn_perm(uo, ue, 0x07060302u);  // hi16 pair pack
  }
  u32x4* wp = (u32x4*)(bfb + r * BF_STRIDE + cb * 16);
  wp[0] = (u32x4){d[0], d[1], d[2], d[3]};
  wp[1] = (u32x4){d[4], d[5], d[6], d[7]};
}

// ---------------------------------------------------------------------------
// Filter: never-drain pipeline, ONE barrier per chunk (r7 structure, 140 µs
// known-good). iter i: stage(i+2)->scr[i&1] | compute(i) from bfb[i&1] |
// vmcnt(5) waits only stage(i+1) (wave-local) | pack(i+1) | lgkmcnt | barrier.
// ---------------------------------------------------------------------------
__global__ __launch_bounds__(NTHRF, 4) void filter_kernel(
    const float* __restrict__ desc, const float* __restrict__ pdb,
    int* __restrict__ cnt, int* __restrict__ cand) {
  __shared__ float tau_s[DQ];
  __shared__ __align__(16) float scr0[CHUNK_FLOATS];
  __shared__ __align__(16) float scr1[CHUNK_FLOATS];
  __shared__ __align__(16) short bfb0[BFB_SHORTS];
  __shared__ __align__(16) short bfb1[BFB_SHORTS];

  const int t = threadIdx.x;
  const int w = t >> 6;       // wave 0..3
  const int lane = t & 63;
  const int r16 = lane & 15;  // db-row within 16-tile (C col)
  const int kg = lane >> 4;   // k-group / C row-group

  const int bid = blockIdx.x;
  const int C = (NCHUNK - bid + GRIDF - 1) / GRIDF;

  // Fused prep: tau[q] = 3.8*||desc_q|| - 2.0 (cut ~3.62 sigma; true top-10
  // ~4.26 sigma; margin covers bf16 A(RNE)+B(trunc) dot error).
  if (t < DQ) {
    const float4* dp = (const float4*)(desc + t * CDIM);
    float ssq = 0.f;
#pragma unroll
    for (int c = 0; c < 32; ++c) {
      const float4 v = dp[c];
      ssq = fmaf(v.x, v.x, ssq);
      ssq = fmaf(v.y, v.y, ssq);
      ssq = fmaf(v.z, v.z, ssq);
      ssq = fmaf(v.w, v.w, ssq);
    }
    tau_s[t] = 3.8f * sqrtf(ssq) - 2.0f;
  }

  // A fragments: wave w owns qtiles {2w, 2w+1} (queries 32w..32w+31).
  bf16x8 afrag[2][4];
#pragma unroll
  for (int qt = 0; qt < 2; ++qt) {
    const int q = (2 * w + qt) * 16 + r16;
#pragma unroll
    for (int ks = 0; ks < 4; ++ks) {
      const float* ap = desc + q * CDIM + ks * 32 + kg * 8;
      bf16x8 a;
#pragma unroll
      for (int j = 0; j < 8; ++j) a[j] = f2bf_rne(ap[j]);
      afrag[qt][ks] = a;
    }
  }

  // All desc vmem loads retired -> counted staging vmcnt is exact from here.
  asm volatile("s_waitcnt vmcnt(0)" ::: "memory");

  // Prologue: stage(0), stage(1); wait stage(0) only; pack(0); publish.
  stage32(pdb + (size_t)bid * CHUNK_FLOATS, scr0, w, lane);
  if (C > 1) {
    stage32(pdb + (size_t)(bid + GRIDF) * CHUNK_FLOATS, scr1, w, lane);
    asm volatile("s_waitcnt vmcnt(5)" ::: "memory");
  } else {
    asm volatile("s_waitcnt vmcnt(0)" ::: "memory");
  }
  pack32(scr0, bfb0, w, lane);
  asm volatile("s_waitcnt lgkmcnt(0)" ::: "memory");
  __builtin_amdgcn_s_barrier();  // bfb0 + tau published
  asm volatile("" ::: "memory");

  float tau_l[2][4];
#pragma unroll
  for (int qt = 0; qt < 2; ++qt)
#pragma unroll
    for (int r = 0; r < 4; ++r)
      tau_l[qt][r] = tau_s[(2 * w + qt) * 16 + kg * 4 + r];

  for (int i = 0; i < C; ++i) {
    const int chunk = bid + i * GRIDF;
    float* scr_st = (i & 1) ? scr1 : scr0;        // stage(i+2) dest
    const float* scr_pk = (i & 1) ? scr0 : scr1;  // pack(i+1) src
    const short* bf_cm = (i & 1) ? bfb1 : bfb0;   // compute src
    short* bf_pk = (i & 1) ? bfb0 : bfb1;         // pack dest
    const bool have2 = (i + 2 < C);

    if (have2)
      stage32(pdb + (size_t)(chunk + 2 * GRIDF) * CHUNK_FLOATS, scr_st, w, lane);

    // compute(i): 8 x { ds_read_b128 ; 2 MFMA }  (loads in flight throughout)
    f32x4 acc[2][2];
    acc[0][0] = (f32x4){0.f, 0.f, 0.f, 0.f};
    acc[0][1] = (f32x4){0.f, 0.f, 0.f, 0.f};
    acc[1][0] = (f32x4){0.f, 0.f, 0.f, 0.f};
    acc[1][1] = (f32x4){0.f, 0.f, 0.f, 0.f};
#pragma unroll
    for (int ks = 0; ks < 4; ++ks) {
#pragma unroll
      for (int rt = 0; rt < 2; ++rt) {
        const bf16x8 b =
            *(const bf16x8*)(bf_cm + (rt * 16 + r16) * BF_STRIDE + ks * 32 + kg * 8);
        acc[0][rt] =
            __builtin_amdgcn_mfma_f32_16x16x32_bf16(afrag[0][ks], b, acc[0][rt], 0, 0, 0);
        acc[1][rt] =
            __builtin_amdgcn_mfma_f32_16x16x32_bf16(afrag[1][ks], b, acc[1][rt], 0, 0, 0);
      }
    }

    // Threshold filter + append (pass rate ~1.5e-4).
#pragma unroll
    for (int qt = 0; qt < 2; ++qt)
#pragma unroll
      for (int rt = 0; rt < 2; ++rt)
#pragma unroll
        for (int reg = 0; reg < 4; ++reg) {
          const float sim = acc[qt][rt][reg];
          if (sim >= tau_l[qt][reg]) {
            const int q = (2 * w + qt) * 16 + kg * 4 + reg;
            const int row = chunk * CHUNK + rt * 16 + r16;
            const int pos = atomicAdd(&cnt[q], 1);
            if (pos < CAP) cand[q * CAP + pos] = row;
          }
        }

    // Wait ONLY stage(i+1) (this wave's 5; i+2's 5 remain outstanding).
    if (have2)
      asm volatile("s_waitcnt vmcnt(5)" ::: "memory");
    else
      asm volatile("s_waitcnt vmcnt(0)" ::: "memory");

    if (i + 1 < C) pack32(scr_pk, bf_pk, w, lane);

    asm volatile("s_waitcnt lgkmcnt(0)" ::: "memory");
    __builtin_amdgcn_s_barrier();  // bfb[(i+1)&1] published
    asm volatile("" ::: "memory");
  }
}

// ---------------------------------------------------------------------------
// Finalize v2: one block (8 waves) per query. Wave-cooperative exact fp32
// rescore: per candidate, lane l loads xp[l], xp[l+64] (two coalesced dword
// streams), 2 FMA vs LDS dq, 6-step shfl reduce; 4 candidates in flight.
// Then wave-0 top-10 (shfl argmax rounds) + exact reference voting on lane 0.
// ---------------------------------------------------------------------------
__global__ __launch_bounds__(512) void finalize_kernel(
    const float* __restrict__ boxes, const float* __restrict__ desc,
    const float* __restrict__ pdb, const int* __restrict__ cnt,
    const int* __restrict__ cand, float* __restrict__ out) {
  const int q = blockIdx.x;
  const int t = threadIdx.x;
  const int wav = t >> 6;  // 0..7
  const int lane = t & 63;
  __shared__ float dq[CDIM];
  __shared__ float simsL[CAP];
  __shared__ int idxL[CAP];

  if (t < CDIM) dq[t] = desc[q * CDIM + t];
  __syncthreads();

  int n = cnt[q];
  if (n > CAP) n = CAP;

  const float dql = dq[lane];
  const float dqh = dq[lane + 64];
  const int base_q = q * CAP;

  // 8 waves x 4-deep unroll: wave handles ci = wav + 8u + 32j.
  for (int ci0 = wav; ci0 < n; ci0 += 32) {
    int r[4];
#pragma unroll
    for (int u = 0; u < 4; ++u) {
      const int ci = ci0 + 8 * u;
      r[u] = cand[base_q + ((ci < n) ? ci : ci0)];
    }
    float a[4], b[4];
#pragma unroll
    for (int u = 0; u < 4; ++u) {
      const float* xp = pdb + (size_t)r[u] * ROW_F;
      a[u] = xp[lane];
      b[u] = xp[lane + 64];
    }
#pragma unroll
    for (int u = 0; u < 4; ++u) {
      const int ci = ci0 + 8 * u;
      float part = fmaf(dql, a[u], dqh * b[u]);
#pragma unroll
      for (int off = 32; off; off >>= 1) part += __shfl_xor(part, off);
      if (ci < n && lane == 0) {
        simsL[ci] = part;
        idxL[ci] = r[u];
      }
    }
  }
  __syncthreads();

  if (t < 4) out[q * 4 + t] = boxes[q * 4 + t];

  if (wav == 0) {
    // Wave-parallel top-10 (knockout rounds, wave-internal LDS ordering).
    float ts[NTOP];
    int ti[NTOP];
#pragma unroll
    for (int k = 0; k < NTOP; ++k) {
      float bv = -3e38f;
      int ba = -1;
      for (int ci = lane; ci < n; ci += 64)
        if (simsL[ci] > bv) { bv = simsL[ci]; ba = ci; }
#pragma unroll
      for (int off = 32; off; off >>= 1) {
        const float ov = __shfl_xor(bv, off);
        const int oa = __shfl_xor(ba, off);
        if (ov > bv) { bv = ov; ba = oa; }
      }
      ts[k] = bv;
      ti[k] = (ba >= 0) ? idxL[ba] : -1;
      if (lane == 0 && ba >= 0) simsL[ba] = -3e38f;
    }

    if (lane == 0) {
      int pl[NTOP];
      bool mk[NTOP];
      int n_kept = 0;
#pragma unroll
      for (int k = 0; k < NTOP; ++k) {
        pl[k] = (ti[k] >= 0) ? (int)pdb[(size_t)ti[k] * ROW_F + CDIM] : -2;
        mk[k] = (ti[k] >= 0) && (ts[k] >= MIN_SIM_F);
        n_kept += mk[k] ? 1 : 0;
      }
      int maxc = 0;
      int counts[NTOP];
#pragma unroll
      for (int j = 0; j < NTOP; ++j) {
        int cj = 0;
        if (mk[j]) {
#pragma unroll
          for (int k = 0; k < NTOP; ++k)
            if (mk[k] && pl[k] == pl[j]) cj++;
        }
        counts[j] = cj;
        if (cj > maxc) maxc = cj;
      }
      const int BIGC = 1 << 30;
      int majority = BIGC;
#pragma unroll
      for (int j = 0; j < NTOP; ++j)
        if (mk[j] && counts[j] == maxc && pl[j] < majority) majority = pl[j];
      const bool valid = (n_kept > 0);  // MIN_VOTES == 0
      const int cls = valid ? majority : -1;
      bool any = false;
      float best = -3e38f;
#pragma unroll
      for (int k = 0; k < NTOP; ++k)
        if (pl[k] == cls) {
          any = true;
          if (ts[k] > best) best = ts[k];
        }
      const float score = (valid && any) ? best : 0.f;
      out[512 + q] = score;
      out[640 + q] = (float)cls;
    }
  }
}

extern "C" void kernel_launch(void* const* d_in, const int* in_sizes, int n_in,
                              void* d_out, int out_size, void* d_ws,
                              size_t ws_size, hipStream_t stream) {
  (void)in_sizes; (void)n_in; (void)out_size; (void)ws_size;
  const float* boxes = (const float*)d_in[0];
  const float* desc = (const float*)d_in[3];
  const float* pdb = (const float*)d_in[4];
  float* out = (float*)d_out;

  // ws layout: cnt[128] i32 @0 | cand[128*CAP] i32 @512
  int* cnt = (int*)d_ws;
  int* cand = (int*)((char*)d_ws + 512);

  hipMemsetAsync(cnt, 0, DQ * sizeof(int), stream);
  filter_kernel<<<GRIDF, NTHRF, 0, stream>>>(desc, pdb, cnt, cand);
  finalize_kernel<<<DQ, 512, 0, stream>>>(boxes, desc, pdb, cnt, cand, out);
}

// Round 10
// 132.402 us; speedup vs baseline: 2.3058x; 1.0647x over previous
//
#include <hip/hip_runtime.h>
#include <stdint.h>

#define DQ 128
#define CDIM 128
#define ROW_F 129              // places_db row stride in floats (128 + place_id)
#define N_DB 1000000
#define CHUNK 32               // db rows per chunk
#define NCHUNK (N_DB / CHUNK)  // 31250 exact
#define GRIDF 768              // 3 blocks/CU (LDS-capped)
#define NTHRF 256              // 4 waves/block -> 12 waves/CU
#define CHUNK_FLOATS (CHUNK * ROW_F)    // 4128 floats = 16512 B
#define BF_STRIDE 136                   // shorts per row (272 B) -> aligned + conflict-free b128
#define BFB_SHORTS (CHUNK * BF_STRIDE)  // 4352 shorts = 8704 B
#define CAP 512
#define NTOP 10
#define MIN_SIM_F 0.8f

typedef __attribute__((ext_vector_type(8))) short bf16x8;
typedef __attribute__((ext_vector_type(4))) float f32x4;
typedef __attribute__((ext_vector_type(4))) uint32_t u32x4;

// fp32 -> bf16 bits, round-to-nearest-even (A side only, once)
__device__ __forceinline__ short f2bf_rne(float x) {
  uint32_t u = __float_as_uint(x);
  u += 0x7FFFu + ((u >> 16) & 1u);
  return (short)(u >> 16);
}

// ---------------------------------------------------------------------------
// Wave-private pack (r7, unchanged): wave w packs ITS OWN rows 8w..8w+7 from
// f32 scratch to the bf16 tile (trunc via v_perm). Lane l: row 8w+(l>>3),
// 16 cols at (l&7)*16.
// ---------------------------------------------------------------------------
__device__ __forceinline__ void pack32(const float* scr, short* bfb, int w,
                                       int lane) {
  const int r = 8 * w + (lane >> 3);
  const int cb = lane & 7;
  const float* rp = scr + r * ROW_F + cb * 16;
  uint32_t d[8];
#pragma unroll
  for (int i = 0; i < 8; ++i) {
    const uint32_t ue = __float_as_uint(rp[2 * i]);
    const uint32_t uo = __float_as_uint(rp[2 * i + 1]);
    d[i] = __builtin_amdgcn_perm(uo, ue, 0x07060302u);  // hi16 pair pack
  }
  u32x4* wp = (u32x4*)(bfb + r * BF_STRIDE + cb * 16);
  wp[0] = (u32x4){d[0], d[1], d[2], d[3]};
  wp[1] = (u32x4){d[4], d[5], d[6], d[7]};
}

// Wave-private span staging via REGISTER loads (H-DMA A/B vs r7's
// global_load_lds). Wave w owns floats [1032w, 1032w+1032) of the chunk
// = rows 8w..8w+7 exactly. 4 full dwordx4 + 1 tail (lanes 0-1).
#define LOADS(cc, R0, R1, R2, R3, RT)                                          \
  do {                                                                         \
    const float4* ps_ =                                                        \
        (const float4*)(pdb + (size_t)(cc)*CHUNK_FLOATS) + 258 * w;            \
    R0 = ps_[lane];                                                            \
    R1 = ps_[64 + lane];                                                       \
    R2 = ps_[128 + lane];                                                      \
    R3 = ps_[192 + lane];                                                      \
    if (lane < 2) RT = ps_[256 + lane];                                        \
  } while (0)

// Matching ds_write_b128 store of the span into linear f32 scratch.
// Compiler auto-inserts the counted vmcnt for exactly these registers.
#define WRITES(scr_, R0, R1, R2, R3, RT)                                       \
  do {                                                                         \
    float4* qs_ = (float4*)(scr_) + 258 * w;                                   \
    qs_[lane] = R0;                                                            \
    qs_[64 + lane] = R1;                                                       \
    qs_[128 + lane] = R2;                                                      \
    qs_[192 + lane] = R3;                                                      \
    if (lane < 2) qs_[256 + lane] = RT;                                        \
  } while (0)

#define LGKM0() asm volatile("s_waitcnt lgkmcnt(0)" ::: "memory")
#define BARRIER()                                                              \
  do {                                                                         \
    __builtin_amdgcn_s_barrier();                                              \
    asm volatile("" ::: "memory");                                             \
  } while (0)

// Compute one chunk from a bf16 tile + threshold-append (r7, unchanged).
#define COMPUTE_CHUNK(bf_cm, chunkidx)                                         \
  do {                                                                         \
    f32x4 acc[2][2];                                                           \
    acc[0][0] = (f32x4){0.f, 0.f, 0.f, 0.f};                                   \
    acc[0][1] = (f32x4){0.f, 0.f, 0.f, 0.f};                                   \
    acc[1][0] = (f32x4){0.f, 0.f, 0.f, 0.f};                                   \
    acc[1][1] = (f32x4){0.f, 0.f, 0.f, 0.f};                                   \
    _Pragma("unroll") for (int ks = 0; ks < 4; ++ks) {                         \
      _Pragma("unroll") for (int rt = 0; rt < 2; ++rt) {                       \
        const bf16x8 b = *(const bf16x8*)((bf_cm) + (rt * 16 + r16) *          \
                                              BF_STRIDE + ks * 32 + kg * 8);   \
        acc[0][rt] = __builtin_amdgcn_mfma_f32_16x16x32_bf16(                  \
            afrag[0][ks], b, acc[0][rt], 0, 0, 0);                             \
        acc[1][rt] = __builtin_amdgcn_mfma_f32_16x16x32_bf16(                  \
            afrag[1][ks], b, acc[1][rt], 0, 0, 0);                             \
      }                                                                        \
    }                                                                          \
    _Pragma("unroll") for (int qt = 0; qt < 2; ++qt)                           \
        _Pragma("unroll") for (int rt = 0; rt < 2; ++rt)                       \
            _Pragma("unroll") for (int reg = 0; reg < 4; ++reg) {              \
      const float sim = acc[qt][rt][reg];                                      \
      if (sim >= tau_l[qt][reg]) {                                             \
        const int q = (2 * w + qt) * 16 + kg * 4 + reg;                        \
        const int row = (chunkidx)*CHUNK + rt * 16 + r16;                      \
        const int pos = atomicAdd(&cnt[q], 1);                                 \
        if (pos < CAP) cand[q * CAP + pos] = row;                              \
      }                                                                        \
    }                                                                          \
  } while (0)

// ---------------------------------------------------------------------------
// Filter: r7 schedule with register-load staging (H-DMA isolation A/B).
// Per body: issue reg-loads for chunk+2 (pinned in-body by the barrier
// fences); compute current chunk from bfb; ds_write the chunk+1 regs into
// f32 scratch (compiler-counted vmcnt leaves chunk+2 loads in flight);
// pack scratch -> bf16 tile; one barrier.
// ---------------------------------------------------------------------------
__global__ __launch_bounds__(NTHRF, 3) void filter_kernel(
    const float* __restrict__ desc, const float* __restrict__ pdb,
    int* __restrict__ cnt, int* __restrict__ cand) {
  __shared__ float tau_s[DQ];
  __shared__ __align__(16) float scr0[CHUNK_FLOATS];
  __shared__ __align__(16) float scr1[CHUNK_FLOATS];
  __shared__ __align__(16) short bfb0[BFB_SHORTS];
  __shared__ __align__(16) short bfb1[BFB_SHORTS];

  const int t = threadIdx.x;
  const int w = t >> 6;       // wave 0..3
  const int lane = t & 63;
  const int r16 = lane & 15;  // db-row within 16-tile (C col)
  const int kg = lane >> 4;   // k-group / C row-group

  const int bid = blockIdx.x;
  const int C = (NCHUNK - bid + GRIDF - 1) / GRIDF;

  float4 rA0{}, rA1{}, rA2{}, rA3{}, rAt{};
  float4 rB0{}, rB1{}, rB2{}, rB3{}, rBt{};

  // Chunk 0/1 loads in flight ASAP (register destinations).
  LOADS(bid, rA0, rA1, rA2, rA3, rAt);
  if (C > 1) LOADS(bid + GRIDF, rB0, rB1, rB2, rB3, rBt);

  // Fused prep: tau[q] = 3.8*||desc_q|| - 2.0 (cut ~3.62 sigma; true top-10
  // ~4.26 sigma; margin covers bf16 A(RNE)+B(trunc) dot error).
  if (t < DQ) {
    const float4* dp = (const float4*)(desc + t * CDIM);
    float ssq = 0.f;
#pragma unroll
    for (int c = 0; c < 32; ++c) {
      const float4 v = dp[c];
      ssq = fmaf(v.x, v.x, ssq);
      ssq = fmaf(v.y, v.y, ssq);
      ssq = fmaf(v.z, v.z, ssq);
      ssq = fmaf(v.w, v.w, ssq);
    }
    tau_s[t] = 3.8f * sqrtf(ssq) - 2.0f;
  }

  // A fragments: wave w owns qtiles {2w, 2w+1} (queries 32w..32w+31).
  bf16x8 afrag[2][4];
#pragma unroll
  for (int qt = 0; qt < 2; ++qt) {
    const int q = (2 * w + qt) * 16 + r16;
#pragma unroll
    for (int ks = 0; ks < 4; ++ks) {
      const float* ap = desc + q * CDIM + ks * 32 + kg * 8;
      bf16x8 a;
#pragma unroll
      for (int j = 0; j < 8; ++j) a[j] = f2bf_rne(ap[j]);
      afrag[qt][ks] = a;
    }
  }

  // Prologue: land chunk 0 (auto-wait), pack, publish (tau too).
  WRITES(scr0, rA0, rA1, rA2, rA3, rAt);
  LGKM0();
  pack32(scr0, bfb0, w, lane);
  LGKM0();
  BARRIER();

  float tau_l[2][4];
#pragma unroll
  for (int qt = 0; qt < 2; ++qt)
#pragma unroll
    for (int r = 0; r < 4; ++r)
      tau_l[qt][r] = tau_s[(2 * w + qt) * 16 + kg * 4 + r];

  for (int i = 0; i < C; i += 2) {
    // ---- even body: compute chunk i (bfb0); stage i+1 regsB; load i+2->A --
    if (i + 2 < C) LOADS(bid + (size_t)(i + 2) * GRIDF, rA0, rA1, rA2, rA3, rAt);
    COMPUTE_CHUNK(bfb0, bid + i * GRIDF);
    if (i + 1 < C) {
      WRITES(scr1, rB0, rB1, rB2, rB3, rBt);  // auto-vmcnt: waits only B regs
      LGKM0();
      pack32(scr1, bfb1, w, lane);
    }
    LGKM0();
    BARRIER();  // bfb1 published
    if (i + 1 >= C) break;

    // ---- odd body: compute chunk i+1 (bfb1); stage i+2 regsA; load i+3->B -
    if (i + 3 < C) LOADS(bid + (size_t)(i + 3) * GRIDF, rB0, rB1, rB2, rB3, rBt);
    COMPUTE_CHUNK(bfb1, bid + (i + 1) * GRIDF);
    if (i + 2 < C) {
      WRITES(scr0, rA0, rA1, rA2, rA3, rAt);
      LGKM0();
      pack32(scr0, bfb0, w, lane);
    }
    LGKM0();
    BARRIER();  // bfb0 published
  }
}

// ---------------------------------------------------------------------------
// Finalize (r9, unchanged): one block (8 waves) per query; wave-cooperative
// exact fp32 rescore; wave-0 top-10 + exact reference voting on lane 0.
// ---------------------------------------------------------------------------
__global__ __launch_bounds__(512) void finalize_kernel(
    const float* __restrict__ boxes, const float* __restrict__ desc,
    const float* __restrict__ pdb, const int* __restrict__ cnt,
    const int* __restrict__ cand, float* __restrict__ out) {
  const int q = blockIdx.x;
  const int t = threadIdx.x;
  const int wav = t >> 6;  // 0..7
  const int lane = t & 63;
  __shared__ float dq[CDIM];
  __shared__ float simsL[CAP];
  __shared__ int idxL[CAP];

  if (t < CDIM) dq[t] = desc[q * CDIM + t];
  __syncthreads();

  int n = cnt[q];
  if (n > CAP) n = CAP;

  const float dql = dq[lane];
  const float dqh = dq[lane + 64];
  const int base_q = q * CAP;

  for (int ci0 = wav; ci0 < n; ci0 += 32) {
    int r[4];
#pragma unroll
    for (int u = 0; u < 4; ++u) {
      const int ci = ci0 + 8 * u;
      r[u] = cand[base_q + ((ci < n) ? ci : ci0)];
    }
    float a[4], b[4];
#pragma unroll
    for (int u = 0; u < 4; ++u) {
      const float* xp = pdb + (size_t)r[u] * ROW_F;
      a[u] = xp[lane];
      b[u] = xp[lane + 64];
    }
#pragma unroll
    for (int u = 0; u < 4; ++u) {
      const int ci = ci0 + 8 * u;
      float part = fmaf(dql, a[u], dqh * b[u]);
#pragma unroll
      for (int off = 32; off; off >>= 1) part += __shfl_xor(part, off);
      if (ci < n && lane == 0) {
        simsL[ci] = part;
        idxL[ci] = r[u];
      }
    }
  }
  __syncthreads();

  if (t < 4) out[q * 4 + t] = boxes[q * 4 + t];

  if (wav == 0) {
    float ts[NTOP];
    int ti[NTOP];
#pragma unroll
    for (int k = 0; k < NTOP; ++k) {
      float bv = -3e38f;
      int ba = -1;
      for (int ci = lane; ci < n; ci += 64)
        if (simsL[ci] > bv) { bv = simsL[ci]; ba = ci; }
#pragma unroll
      for (int off = 32; off; off >>= 1) {
        const float ov = __shfl_xor(bv, off);
        const int oa = __shfl_xor(ba, off);
        if (ov > bv) { bv = ov; ba = oa; }
      }
      ts[k] = bv;
      ti[k] = (ba >= 0) ? idxL[ba] : -1;
      if (lane == 0 && ba >= 0) simsL[ba] = -3e38f;
    }

    if (lane == 0) {
      int pl[NTOP];
      bool mk[NTOP];
      int n_kept = 0;
#pragma unroll
      for (int k = 0; k < NTOP; ++k) {
        pl[k] = (ti[k] >= 0) ? (int)pdb[(size_t)ti[k] * ROW_F + CDIM] : -2;
        mk[k] = (ti[k] >= 0) && (ts[k] >= MIN_SIM_F);
        n_kept += mk[k] ? 1 : 0;
      }
      int maxc = 0;
      int counts[NTOP];
#pragma unroll
      for (int j = 0; j < NTOP; ++j) {
        int cj = 0;
        if (mk[j]) {
#pragma unroll
          for (int k = 0; k < NTOP; ++k)
            if (mk[k] && pl[k] == pl[j]) cj++;
        }
        counts[j] = cj;
        if (cj > maxc) maxc = cj;
      }
      const int BIGC = 1 << 30;
      int majority = BIGC;
#pragma unroll
      for (int j = 0; j < NTOP; ++j)
        if (mk[j] && counts[j] == maxc && pl[j] < majority) majority = pl[j];
      const bool valid = (n_kept > 0);  // MIN_VOTES == 0
      const int cls = valid ? majority : -1;
      bool any = false;
      float best = -3e38f;
#pragma unroll
      for (int k = 0; k < NTOP; ++k)
        if (pl[k] == cls) {
          any = true;
          if (ts[k] > best) best = ts[k];
        }
      const float score = (valid && any) ? best : 0.f;
      out[512 + q] = score;
      out[640 + q] = (float)cls;
    }
  }
}

extern "C" void kernel_launch(void* const* d_in, const int* in_sizes, int n_in,
                              void* d_out, int out_size, void* d_ws,
                              size_t ws_size, hipStream_t stream) {
  (void)in_sizes; (void)n_in; (void)out_size; (void)ws_size;
  const float* boxes = (const float*)d_in[0];
  const float* desc = (const float*)d_in[3];
  const float* pdb = (const float*)d_in[4];
  float* out = (float*)d_out;

  // ws layout: cnt[128] i32 @0 | cand[128*CAP] i32 @512
  int* cnt = (int*)d_ws;
  int* cand = (int*)((char*)d_ws + 512);

  hipMemsetAsync(cnt, 0, DQ * sizeof(int), stream);
  filter_kernel<<<GRIDF, NTHRF, 0, stream>>>(desc, pdb, cnt, cand);
  finalize_kernel<<<DQ, 512, 0, stream>>>(boxes, desc, pdb, cnt, cand, out);
}